// Round 10
// baseline (140.942 us; speedup 1.0000x reference)
//
#include <hip/hip_runtime.h>
#include <hip/hip_fp16.h>

#define IMG   512
#define NIMG  32
#define TX    128
#define TY    16
#define NQ    36                  /* staged 4-col strips per block */
#define RSDW  76                  /* sH row stride in dwords (72 data + 4 pad) */
#define PLDW  (TY * RSDW)         /* 1216 dwords per channel plane */
#define VITEMS (NQ * 8)           /* 288 v-pass items */
#define NBX   (IMG / TX)          /* 4 */
#define NBY   (IMG / TY)          /* 32 */
#define NBLK  (NBX * NBY * NIMG)  /* 4096 */
#define NPIX  (32.0f * 512.0f * 512.0f)

constexpr float GW[11] = {
    0.00102838f, 0.00759876f, 0.03600077f, 0.10936069f, 0.21300553f,
    0.26601174f,
    0.21300553f, 0.10936069f, 0.03600077f, 0.00759876f, 0.00102838f
};
constexpr float C1c = 0.0001f;
constexpr float C2c = 0.0009f;

__global__ void ssim_init_out(float* __restrict__ out) { out[0] = 1.0f; }

__device__ __forceinline__ float4 f4mul(float4 a, float4 b) {
    return make_float4(a.x * b.x, a.y * b.y, a.z * b.z, a.w * b.w);
}
__device__ __forceinline__ float4 f4fma(float w, float4 v, float4 c) {
    return make_float4(fmaf(w, v.x, c.x), fmaf(w, v.y, c.y),
                       fmaf(w, v.z, c.z), fmaf(w, v.w, c.w));
}

// pack two fp32 -> one dword of fp16 pair (v_cvt_pkrtz_f16_f32).
// NOTE: on this ROCm the builtin returns an ext_vector of __fp16 (not
// _Float16) — use a matching type and bit-copy out.
__device__ __forceinline__ unsigned int pkrtz(float x, float y) {
#if __has_builtin(__builtin_amdgcn_cvt_pkrtz)
    typedef __attribute__((ext_vector_type(2))) __fp16 h2v;
    h2v r = __builtin_amdgcn_cvt_pkrtz(x, y);
    union { h2v h; unsigned int u; } c; c.h = r; return c.u;
#else
    __half2 h = __halves2half2(__float2half_rn(x), __float2half_rn(y));
    union { __half2 h; unsigned int u; } c; c.h = h; return c.u;
#endif
}
__device__ __forceinline__ __half2 u2h(unsigned int u) {
    union { unsigned int u; __half2 h; } c; c.u = u; return c.h;
}
#define HWC(k) __half2half2(__float2half_rn(GW[k]))

// One v-pass item: strip q (4 cols), row-pair g. fp32 vertical convs for 2
// output rows, packed to fp16 in sH (row-major [ch][y][col-pair]).
template <bool INTERIOR>
__device__ __forceinline__ void vpass_item(int it, int X0, int Y0,
        const float* __restrict__ a0, const float* __restrict__ b0,
        unsigned int* __restrict__ sH) {
    const int q  = it % NQ;
    const int g  = it / NQ;
    const int y0 = 2 * g;
    int gx0 = X0 - 8 + 4 * q;
    const int gyb = Y0 + y0 - 5;
    bool okx = true;
    if (!INTERIOR) {
        okx = (gx0 >= 0) && (gx0 + 3 < IMG);
        gx0 = min(max(gx0, 0), IMG - 4);
    }

    float4 acc[5][2];
#pragma unroll
    for (int ch = 0; ch < 5; ++ch)
#pragma unroll
        for (int o = 0; o < 2; ++o)
            acc[ch][o] = make_float4(0.f, 0.f, 0.f, 0.f);

    float4 ra[6], rb[6];
#pragma unroll
    for (int half = 0; half < 2; ++half) {
#pragma unroll
        for (int j = 0; j < 6; ++j) {
            int gy = gyb + half * 6 + j;
            if (!INTERIOR) gy = min(max(gy, 0), IMG - 1);
            const int off = gy * IMG + gx0;
            ra[j] = *(const float4*)(a0 + off);
            rb[j] = *(const float4*)(b0 + off);
        }
#pragma unroll
        for (int j = 0; j < 6; ++j) {
            const int k = half * 6 + j;
            const float4 a = ra[j];
            const float4 b = rb[j];
            const float4 aa = f4mul(a, a);
            const float4 bb = f4mul(b, b);
            const float4 ab = f4mul(a, b);
            if (INTERIOR) {
                if (k <= 10) {
                    const float w = GW[k];
                    acc[0][0] = f4fma(w, a,  acc[0][0]);
                    acc[1][0] = f4fma(w, b,  acc[1][0]);
                    acc[2][0] = f4fma(w, aa, acc[2][0]);
                    acc[3][0] = f4fma(w, bb, acc[3][0]);
                    acc[4][0] = f4fma(w, ab, acc[4][0]);
                }
                if (k >= 1) {
                    const float w = GW[k - 1];
                    acc[0][1] = f4fma(w, a,  acc[0][1]);
                    acc[1][1] = f4fma(w, b,  acc[1][1]);
                    acc[2][1] = f4fma(w, aa, acc[2][1]);
                    acc[3][1] = f4fma(w, bb, acc[3][1]);
                    acc[4][1] = f4fma(w, ab, acc[4][1]);
                }
            } else {
                const int gy = gyb + k;
                const bool ok = okx && ((unsigned)gy < IMG);
                float w0 = (k <= 10) ? GW[k] : 0.0f;
                float w1 = (k >= 1) ? GW[k - 1] : 0.0f;
                w0 = ok ? w0 : 0.0f;
                w1 = ok ? w1 : 0.0f;
                acc[0][0] = f4fma(w0, a,  acc[0][0]);
                acc[1][0] = f4fma(w0, b,  acc[1][0]);
                acc[2][0] = f4fma(w0, aa, acc[2][0]);
                acc[3][0] = f4fma(w0, bb, acc[3][0]);
                acc[4][0] = f4fma(w0, ab, acc[4][0]);
                acc[0][1] = f4fma(w1, a,  acc[0][1]);
                acc[1][1] = f4fma(w1, b,  acc[1][1]);
                acc[2][1] = f4fma(w1, aa, acc[2][1]);
                acc[3][1] = f4fma(w1, bb, acc[3][1]);
                acc[4][1] = f4fma(w1, ab, acc[4][1]);
            }
        }
    }
    // pack fp32 -> fp16 pairs; ds_write_b64 per (ch,row)
#pragma unroll
    for (int o = 0; o < 2; ++o) {
        const int y = y0 + o;
#pragma unroll
        for (int ch = 0; ch < 5; ++ch) {
            const float4 A = acc[ch][o];
            uint2 p;
            p.x = pkrtz(A.x, A.y);
            p.y = pkrtz(A.z, A.w);
            *(uint2*)&sH[ch * PLDW + y * RSDW + 2 * q] = p;
        }
    }
}

__global__ __launch_bounds__(256, 3) void ssim_fused(
        const float* __restrict__ img1, const float* __restrict__ img2,
        float* __restrict__ ws, float* __restrict__ out) {
    // fp16 v-conv intermediate: 5 ch x 16 rows x 76 dwords = 24.32 KB
    // -> 6 blocks/CU.
    __shared__ unsigned int sH[5 * PLDW];

    const int tid = threadIdx.x;
    const int X0 = blockIdx.x * TX;
    const int Y0 = blockIdx.y * TY;
    const int n  = blockIdx.z;
    const float* a0 = img1 + (size_t)n * IMG * IMG;
    const float* b0 = img2 + (size_t)n * IMG * IMG;

    const bool interior = (X0 >= 8) && (X0 - 8 + 4 * (NQ - 1) + 3 < IMG) &&
                          (Y0 >= 5) && (Y0 + TY + 4 < IMG);

    if (interior) {
        for (int it = tid; it < VITEMS; it += 256)
            vpass_item<true>(it, X0, Y0, a0, b0, sH);
    } else {
        for (int it = tid; it < VITEMS; it += 256)
            vpass_item<false>(it, X0, Y0, a0, b0, sH);
    }
    __syncthreads();

    // ---- horizontal pass (packed half2) + ssim: 8 out cols/thread ----
    // thread (y = tid&15, grp = tid>>4): out cols 8g..8g+7.
    // staged local cols 8g..8g+23 live in dwords v[0..11] (col-pairs).
    float sum = 0.0f;
    {
        const int y = tid & 15;
        const int g = tid >> 4;
        float res[5][8];
#pragma unroll
        for (int ch = 0; ch < 5; ++ch) {
            const unsigned int* base = &sH[ch * PLDW + y * RSDW + 4 * g];
            const uint4 r0 = *(const uint4*)(base);
            const uint4 r1 = *(const uint4*)(base + 4);
            const uint4 r2 = *(const uint4*)(base + 8);
            unsigned int v[12] = { r0.x, r0.y, r0.z, r0.w,
                                   r1.x, r1.y, r1.z, r1.w,
                                   r2.x, r2.y, r2.z, r2.w };
            unsigned int sh[10];
#pragma unroll
            for (int m = 1; m <= 9; ++m)
                sh[m] = __builtin_amdgcn_alignbit(v[m + 1], v[m], 16);
            // output pair j: cols (2j, 2j+1); tap k uses pair start c=2j+3+k:
            // odd c -> sh[(c-1)/2], even c -> v[c/2]
#pragma unroll
            for (int j = 0; j < 4; ++j) {
                __half2 acc = __hmul2(HWC(0), u2h(sh[j + 1]));
                acc = __hfma2(HWC(1),  u2h(v[j + 2]),  acc);
                acc = __hfma2(HWC(2),  u2h(sh[j + 2]), acc);
                acc = __hfma2(HWC(3),  u2h(v[j + 3]),  acc);
                acc = __hfma2(HWC(4),  u2h(sh[j + 3]), acc);
                acc = __hfma2(HWC(5),  u2h(v[j + 4]),  acc);
                acc = __hfma2(HWC(6),  u2h(sh[j + 4]), acc);
                acc = __hfma2(HWC(7),  u2h(v[j + 5]),  acc);
                acc = __hfma2(HWC(8),  u2h(sh[j + 5]), acc);
                acc = __hfma2(HWC(9),  u2h(v[j + 6]),  acc);
                acc = __hfma2(HWC(10), u2h(sh[j + 6]), acc);
                res[ch][2 * j]     = __low2float(acc);
                res[ch][2 * j + 1] = __high2float(acc);
            }
        }
#pragma unroll
        for (int e = 0; e < 8; ++e) {
            const float mu1 = res[0][e], mu2 = res[1][e];
            const float m1s = mu1 * mu1;
            const float m2s = mu2 * mu2;
            const float m12 = mu1 * mu2;
            const float s1  = res[2][e] - m1s;
            const float s2  = res[3][e] - m2s;
            const float s12 = res[4][e] - m12;
            const float num = (2.0f * m12 + C1c) * (2.0f * s12 + C2c);
            const float den = (m1s + m2s + C1c) * (s1 + s2 + C2c);
            sum += num * __builtin_amdgcn_rcpf(den);
        }
    }

    // ---- block reduction ----
#pragma unroll
    for (int off = 32; off > 0; off >>= 1)
        sum += __shfl_down(sum, off, 64);

    __shared__ float wred[4];
    if ((tid & 63) == 0) wred[tid >> 6] = sum;
    __syncthreads();
    if (tid == 0) {
        const float s = wred[0] + wred[1] + wred[2] + wred[3];
        if (ws) {
            const int bid = blockIdx.x +
                (int)gridDim.x * (blockIdx.y + (int)gridDim.y * blockIdx.z);
            ws[bid] = s;
        } else {
            atomicAdd(out, -s * (1.0f / NPIX));
        }
    }
}

__global__ __launch_bounds__(1024) void ssim_reduce(
        const float* __restrict__ ws, float* __restrict__ out) {
    const int t = threadIdx.x;
    float s = 0.0f;
    for (int i = t; i < NBLK; i += 1024) s += ws[i];
#pragma unroll
    for (int off = 32; off > 0; off >>= 1)
        s += __shfl_down(s, off, 64);
    __shared__ float wr[16];
    if ((t & 63) == 0) wr[t >> 6] = s;
    __syncthreads();
    if (t < 64) {
        float v = (t < 16) ? wr[t] : 0.0f;
#pragma unroll
        for (int off = 8; off > 0; off >>= 1)
            v += __shfl_down(v, off, 64);
        if (t == 0) out[0] = 1.0f - v * (1.0f / NPIX);
    }
}

extern "C" void kernel_launch(void* const* d_in, const int* in_sizes, int n_in,
                              void* d_out, int out_size, void* d_ws, size_t ws_size,
                              hipStream_t stream) {
    const float* img1 = (const float*)d_in[0];
    const float* img2 = (const float*)d_in[1];
    float* out = (float*)d_out;
    const bool two_stage = (d_ws != nullptr) && (ws_size >= NBLK * sizeof(float));
    float* ws = two_stage ? (float*)d_ws : nullptr;

    if (!two_stage) ssim_init_out<<<1, 1, 0, stream>>>(out);

    dim3 grid(NBX, NBY, NIMG);   // 4 x 32 x 32 = 4096 blocks
    ssim_fused<<<grid, 256, 0, stream>>>(img1, img2, ws, out);

    if (two_stage) ssim_reduce<<<1, 1024, 0, stream>>>(ws, out);
}

// Round 11
// 133.170 us; speedup vs baseline: 1.0584x; 1.0584x over previous
//
#include <hip/hip_runtime.h>

#define IMG   512
#define NIMG  32
#define TX    64
#define TY    16
#define NQ    20                  /* staged 4-col strips per block */
#define VQS   17                  /* sV strip stride in quads (16 rows + 1 pad) */
#define VPL   (NQ * VQS)          /* 340 quads per channel plane */
#define VITEMS (NQ * 8)           /* 160 v-pass items */
#define NBX   (IMG / TX)          /* 8 */
#define NBY   (IMG / TY)          /* 32 */
#define NBLK  (NBX * NBY * NIMG)  /* 8192 */
#define NPIX  (32.0f * 512.0f * 512.0f)

constexpr float GW[11] = {
    0.00102838f, 0.00759876f, 0.03600077f, 0.10936069f, 0.21300553f,
    0.26601174f,
    0.21300553f, 0.10936069f, 0.03600077f, 0.00759876f, 0.00102838f
};
constexpr float C1c = 0.0001f;
constexpr float C2c = 0.0009f;

__global__ void ssim_init_out(float* __restrict__ out) { out[0] = 1.0f; }

__device__ __forceinline__ float4 f4mul(float4 a, float4 b) {
    return make_float4(a.x * b.x, a.y * b.y, a.z * b.z, a.w * b.w);
}
__device__ __forceinline__ float4 f4fma(float w, float4 v, float4 c) {
    return make_float4(fmaf(w, v.x, c.x), fmaf(w, v.y, c.y),
                       fmaf(w, v.z, c.z), fmaf(w, v.w, c.w));
}

// One v-pass item: strip q (4 cols), row-pair g. fp32 vertical convs for 2
// output rows of one float4 strip, written to transposed sV.
// INTERIOR: zero bounds code. Boundary: clamped addresses + weight-kill
// (exact zero-pad semantics).
template <bool INTERIOR>
__device__ __forceinline__ void vpass_item(int tid, int X0, int Y0,
        const float* __restrict__ a0, const float* __restrict__ b0,
        float4* __restrict__ sV4) {
    const int q  = tid % NQ;              // consecutive lanes -> contiguous gmem
    const int g  = tid / NQ;
    const int y0 = 2 * g;
    int gx0 = X0 - 8 + 4 * q;
    const int gyb = Y0 + y0 - 5;
    bool okx = true;
    if (!INTERIOR) {
        okx = (gx0 >= 0) && (gx0 + 3 < IMG);
        gx0 = min(max(gx0, 0), IMG - 4);
    }

    float4 acc[5][2];
#pragma unroll
    for (int ch = 0; ch < 5; ++ch)
#pragma unroll
        for (int o = 0; o < 2; ++o)
            acc[ch][o] = make_float4(0.f, 0.f, 0.f, 0.f);

    float4 ra[6], rb[6];
#pragma unroll
    for (int half = 0; half < 2; ++half) {
        // batch-issue 12 loads (6 rows x 2 images), addresses always valid
#pragma unroll
        for (int j = 0; j < 6; ++j) {
            int gy = gyb + half * 6 + j;
            if (!INTERIOR) gy = min(max(gy, 0), IMG - 1);
            const int off = gy * IMG + gx0;
            ra[j] = *(const float4*)(a0 + off);
            rb[j] = *(const float4*)(b0 + off);
        }
#pragma unroll
        for (int j = 0; j < 6; ++j) {
            const int k = half * 6 + j;
            const float4 a = ra[j];
            const float4 b = rb[j];
            const float4 aa = f4mul(a, a);
            const float4 bb = f4mul(b, b);
            const float4 ab = f4mul(a, b);
            if (INTERIOR) {
                if (k <= 10) {
                    const float w = GW[k];
                    acc[0][0] = f4fma(w, a,  acc[0][0]);
                    acc[1][0] = f4fma(w, b,  acc[1][0]);
                    acc[2][0] = f4fma(w, aa, acc[2][0]);
                    acc[3][0] = f4fma(w, bb, acc[3][0]);
                    acc[4][0] = f4fma(w, ab, acc[4][0]);
                }
                if (k >= 1) {
                    const float w = GW[k - 1];
                    acc[0][1] = f4fma(w, a,  acc[0][1]);
                    acc[1][1] = f4fma(w, b,  acc[1][1]);
                    acc[2][1] = f4fma(w, aa, acc[2][1]);
                    acc[3][1] = f4fma(w, bb, acc[3][1]);
                    acc[4][1] = f4fma(w, ab, acc[4][1]);
                }
            } else {
                const int gy = gyb + k;
                const bool ok = okx && ((unsigned)gy < IMG);
                float w0 = (k <= 10) ? GW[k] : 0.0f;
                float w1 = (k >= 1) ? GW[k - 1] : 0.0f;
                w0 = ok ? w0 : 0.0f;
                w1 = ok ? w1 : 0.0f;
                acc[0][0] = f4fma(w0, a,  acc[0][0]);
                acc[1][0] = f4fma(w0, b,  acc[1][0]);
                acc[2][0] = f4fma(w0, aa, acc[2][0]);
                acc[3][0] = f4fma(w0, bb, acc[3][0]);
                acc[4][0] = f4fma(w0, ab, acc[4][0]);
                acc[0][1] = f4fma(w1, a,  acc[0][1]);
                acc[1][1] = f4fma(w1, b,  acc[1][1]);
                acc[2][1] = f4fma(w1, aa, acc[2][1]);
                acc[3][1] = f4fma(w1, bb, acc[3][1]);
                acc[4][1] = f4fma(w1, ab, acc[4][1]);
            }
        }
    }
    // sV write: lane stride VQS=17 quads -> 17 mod 8 = 1 -> all-distinct
    // bank groups per 8-lane phase (conflict-free b128).
#pragma unroll
    for (int o = 0; o < 2; ++o)
#pragma unroll
        for (int ch = 0; ch < 5; ++ch)
            sV4[ch * VPL + q * VQS + (y0 + o)] = acc[ch][o];
}

__global__ __launch_bounds__(256, 3) void ssim_fused(
        const float* __restrict__ img1, const float* __restrict__ img2,
        float* __restrict__ ws, float* __restrict__ out) {
    // fp32 sV, transposed [ch][strip][row]: 5*340 quads * 16B = 27.2 KB
    // -> 5 blocks/CU (vs 3 at the 128-wide tile). Per-block idle waves in
    // each phase are absorbed by the deeper block overlap.
    __shared__ float4 sV4[5 * VPL];

    const int tid = threadIdx.x;
    const int X0 = blockIdx.x * TX;
    const int Y0 = blockIdx.y * TY;
    const int n  = blockIdx.z;
    const float* a0 = img1 + (size_t)n * IMG * IMG;
    const float* b0 = img2 + (size_t)n * IMG * IMG;

    // Interior iff every load address is naturally in-bounds.
    const bool interior = (X0 >= 8) && (X0 - 8 + 4 * (NQ - 1) + 3 < IMG) &&
                          (Y0 >= 5) && (Y0 + TY + 4 < IMG);

    if (tid < VITEMS) {
        if (interior) vpass_item<true>(tid, X0, Y0, a0, b0, sV4);
        else          vpass_item<false>(tid, X0, Y0, a0, b0, sV4);
    }
    __syncthreads();

    // ---- horizontal pass + ssim: 8 out cols/thread, 128 items.
    // 8-lane phase: y consecutive, strip fixed -> conflict-free b128 reads.
    float sum = 0.0f;
    if (tid < 128) {
        const int y   = tid & 15;      // row 0..15
        const int grp = tid >> 4;      // 8-col group: out cols 8*grp..8*grp+7
        float res[5][8];
#pragma unroll
        for (int ch = 0; ch < 5; ++ch) {
            const float4* base = &sV4[ch * VPL + y];
            float v[24];
#pragma unroll
            for (int d = 0; d < 6; ++d) {
                const float4 t = base[(2 * grp + d) * VQS];
                v[4 * d + 0] = t.x; v[4 * d + 1] = t.y;
                v[4 * d + 2] = t.z; v[4 * d + 3] = t.w;
            }
#pragma unroll
            for (int e = 0; e < 8; ++e) {
                float s = GW[0] * v[e + 3];
#pragma unroll
                for (int k = 1; k < 11; ++k) s = fmaf(GW[k], v[e + 3 + k], s);
                res[ch][e] = s;
            }
        }
#pragma unroll
        for (int e = 0; e < 8; ++e) {
            const float mu1 = res[0][e], mu2 = res[1][e];
            const float m1s = mu1 * mu1;
            const float m2s = mu2 * mu2;
            const float m12 = mu1 * mu2;
            const float s1  = res[2][e] - m1s;
            const float s2  = res[3][e] - m2s;
            const float s12 = res[4][e] - m12;
            const float num = (2.0f * m12 + C1c) * (2.0f * s12 + C2c);
            const float den = (m1s + m2s + C1c) * (s1 + s2 + C2c);
            sum += num * __builtin_amdgcn_rcpf(den);
        }
    }

    // ---- block reduction ----
#pragma unroll
    for (int off = 32; off > 0; off >>= 1)
        sum += __shfl_down(sum, off, 64);

    __shared__ float wred[4];
    if ((tid & 63) == 0) wred[tid >> 6] = sum;
    __syncthreads();
    if (tid == 0) {
        const float s = wred[0] + wred[1] + wred[2] + wred[3];
        if (ws) {
            const int bid = blockIdx.x +
                (int)gridDim.x * (blockIdx.y + (int)gridDim.y * blockIdx.z);
            ws[bid] = s;
        } else {
            atomicAdd(out, -s * (1.0f / NPIX));
        }
    }
}

__global__ __launch_bounds__(1024) void ssim_reduce(
        const float* __restrict__ ws, float* __restrict__ out) {
    const int t = threadIdx.x;
    float s = 0.0f;
    for (int i = t; i < NBLK; i += 1024) s += ws[i];
#pragma unroll
    for (int off = 32; off > 0; off >>= 1)
        s += __shfl_down(s, off, 64);
    __shared__ float wr[16];
    if ((t & 63) == 0) wr[t >> 6] = s;
    __syncthreads();
    if (t < 64) {
        float v = (t < 16) ? wr[t] : 0.0f;
#pragma unroll
        for (int off = 8; off > 0; off >>= 1)
            v += __shfl_down(v, off, 64);
        if (t == 0) out[0] = 1.0f - v * (1.0f / NPIX);
    }
}

extern "C" void kernel_launch(void* const* d_in, const int* in_sizes, int n_in,
                              void* d_out, int out_size, void* d_ws, size_t ws_size,
                              hipStream_t stream) {
    const float* img1 = (const float*)d_in[0];
    const float* img2 = (const float*)d_in[1];
    float* out = (float*)d_out;
    const bool two_stage = (d_ws != nullptr) && (ws_size >= NBLK * sizeof(float));
    float* ws = two_stage ? (float*)d_ws : nullptr;

    if (!two_stage) ssim_init_out<<<1, 1, 0, stream>>>(out);

    dim3 grid(NBX, NBY, NIMG);   // 8 x 32 x 32 = 8192 blocks
    ssim_fused<<<grid, 256, 0, stream>>>(img1, img2, ws, out);

    if (two_stage) ssim_reduce<<<1, 1024, 0, stream>>>(ws, out);
}